// Round 11
// baseline (317.999 us; speedup 1.0000x reference)
//
#include <hip/hip_runtime.h>
#include <hip/hip_bf16.h>

#define B_ 1024
#define L_ 256
#define D_ 256
#define H_ 512
#define U_ 512
#define M_ (B_ * L_)

#define BM 128   // rows per block; block covers ALL of U, full K in LDS

typedef float f32x4 __attribute__((ext_vector_type(4)));
typedef short bf16x8 __attribute__((ext_vector_type(8)));
typedef short bf16x4 __attribute__((ext_vector_type(4)));

__device__ __forceinline__ short f2bf(float f) {
  unsigned u = __float_as_uint(f);
  u += 0x7fffu + ((u >> 16) & 1u);
  return (short)(u >> 16);
}

__device__ __forceinline__ float fast_tanh(float x) {
  float e = __expf(2.0f * x);
  return 1.0f - 2.0f * __builtin_amdgcn_rcpf(e + 1.0f);
}

// ---------------- prep: W1 [D,U] fp32 -> W1F fragment-major bf16 ----------------
// chunk c = nb*8 + kb (nb = u/16, kb = d/32); lane l of chunk c holds
// u = nb*16 + (l&15), d = kb*32 + (l>>4)*8 + j  ->  flat c*512 + l*8 + j.
__global__ void k_w1f(const float* __restrict__ W1, short* __restrict__ W1F) {
  int i = blockIdx.x * 256 + threadIdx.x;   // over 131072
  int jj = i & 7;
  int no = (i >> 3) & 15;
  int kc = (i >> 7) & 3;
  int kb = (i >> 9) & 7;
  int nb = i >> 12;
  int u = nb * 16 + no;
  int d = kb * 32 + kc * 8 + jj;
  W1F[i] = f2bf(W1[(size_t)d * U_ + u]);
}

// ---------------- projh[b,u] = hidden[b,:] @ W2[:,u] + b1[u] + b2[u] ----------------
__global__ void k_projh(const float* __restrict__ hidden, const float* __restrict__ W2,
                        const float* __restrict__ b1, const float* __restrict__ b2,
                        float* __restrict__ ph) {
  int u = blockIdx.x * 256 + threadIdx.x;
  int b0 = blockIdx.y * 8;
  float acc[8] = {0.f, 0.f, 0.f, 0.f, 0.f, 0.f, 0.f, 0.f};
  for (int h = 0; h < H_; ++h) {
    float w = W2[(size_t)h * U_ + u];
#pragma unroll
    for (int i = 0; i < 8; ++i) acc[i] = fmaf(hidden[(size_t)(b0 + i) * H_ + h], w, acc[i]);
  }
  float bias = b1[u] + b2[u];
#pragma unroll
  for (int i = 0; i < 8; ++i) ph[(size_t)(b0 + i) * U_ + u] = acc[i] + bias;
}

// ---------------- main: 128 rows x full U per block, 512 threads = 8 waves ----------------
// Wave (wr,wc): wr in 0..3 owns 32 rows; wc in 0..1 owns the u-half of each ntile.
// acc[2][4] = 32 VGPRs (R10's 64 spilled: WRITE_SIZE 53MB scratch). A staged once
// (full K, bf16, XOR-swizzle, 1 barrier). B direct from L2-resident W1F, 1-kt prefetch.
// wc splits the u-SUM -> cross-wave combine via csum LDS.
__global__ __launch_bounds__(512, 4) void k_gemm(
    const float* __restrict__ F,    // [M_, D_] fp32
    const short* __restrict__ W1F,  // fragment-major bf16
    const float* __restrict__ ph,   // [B_, U_]
    const float* __restrict__ Wv,   // [U_]
    float* __restrict__ logits) {   // [M_]
  __shared__ __align__(16) short As[BM * D_];   // 64 KB
  __shared__ float csum[2][BM];                 // 1 KB

  const int tid = threadIdx.x;
  const int lane = tid & 63;
  const int hi = lane >> 4;
  const int wid = tid >> 6;        // 0..7
  const int wr = wid >> 1;         // 0..3: 32-row group
  const int wc = wid & 1;          // 0..1: u-half
  const int m0 = blockIdx.x * BM;
  const int b = m0 >> 8;

  // ---- stage A: 128x256 fp32 -> bf16 LDS, once (16 f32x4 per thread) ----
  {
    const int q = tid & 63;                      // k-quad (4 floats)
    const float* sp = F + (size_t)(m0 + wid) * D_ + q * 4;
    const int kq8 = q * 8;                       // byte offset of 4-bf16 quad
#pragma unroll
    for (int jb = 0; jb < 2; ++jb) {
      f32x4 sv[8];
#pragma unroll
      for (int j = 0; j < 8; ++j)
        sv[j] = *(const f32x4*)(sp + (size_t)(jb * 8 + j) * 8 * D_);
#pragma unroll
      for (int j = 0; j < 8; ++j) {
        int row = (jb * 8 + j) * 8 + wid;        // each row once across 8 waves
        int boff = (row * 512 + kq8) ^ ((row & 7) << 4);
        bf16x4 w;
#pragma unroll
        for (int qq = 0; qq < 4; ++qq) w[qq] = f2bf(sv[j][qq]);
        *(bf16x4*)((char*)As + boff) = w;
      }
    }
  }
  __syncthreads();

  f32x4 acc[2][4];
  float cs[2][4];
  const f32x4 fz = {0.f, 0.f, 0.f, 0.f};
#pragma unroll
  for (int mi = 0; mi < 2; ++mi)
#pragma unroll
    for (int x = 0; x < 4; ++x) { acc[mi][x] = fz; cs[mi][x] = 0.f; }

  // B chunk(nt,wc,ni,kt) = (nt*64 + wc*32 + ni*8 + kt); addr = chunk*512 + lane*8 (shorts)
  const short* bbase = W1F + (size_t)(wc * 32) * 512 + lane * 8;
  bf16x8 bcur[4], bnxt[4];
#pragma unroll
  for (int ni = 0; ni < 4; ++ni)
    bcur[ni] = *(const bf16x8*)(bbase + (size_t)(ni * 8) * 512);

  const float* phr = ph + (size_t)b * U_;
  const int rbase = wr * 32 + (lane & 15);

  for (int nt = 0; nt < 4; ++nt) {
#pragma unroll
    for (int kt = 0; kt < 8; ++kt) {
      if (nt * 8 + kt < 31) {    // prefetch (nt,kt+1), carries into next nt
        const int ktn = (kt + 1) & 7;
        const int ntn64 = (nt + ((kt + 1) >> 3)) * 64;
#pragma unroll
        for (int ni = 0; ni < 4; ++ni)
          bnxt[ni] = *(const bf16x8*)(bbase + (size_t)(ntn64 + ni * 8 + ktn) * 512);
      }
      bf16x8 af[2];
#pragma unroll
      for (int mi = 0; mi < 2; ++mi) {
        int rA = rbase + mi * 16;
        int boff = (rA * 512 + kt * 64 + hi * 16) ^ ((rA & 7) << 4);
        af[mi] = *(const bf16x8*)((const char*)As + boff);
      }
#pragma unroll
      for (int mi = 0; mi < 2; ++mi) {
        acc[mi][0] = __builtin_amdgcn_mfma_f32_16x16x32_bf16(af[mi], bcur[0], acc[mi][0], 0, 0, 0);
        acc[mi][1] = __builtin_amdgcn_mfma_f32_16x16x32_bf16(af[mi], bcur[1], acc[mi][1], 0, 0, 0);
        acc[mi][2] = __builtin_amdgcn_mfma_f32_16x16x32_bf16(af[mi], bcur[2], acc[mi][2], 0, 0, 0);
        acc[mi][3] = __builtin_amdgcn_mfma_f32_16x16x32_bf16(af[mi], bcur[3], acc[mi][3], 0, 0, 0);
      }
#pragma unroll
      for (int ni = 0; ni < 4; ++ni) bcur[ni] = bnxt[ni];
    }
    // ntile epilogue: cs += tanh(acc + ph) * Wv ; reset acc
#pragma unroll
    for (int ni = 0; ni < 4; ++ni) {
      int u = nt * 128 + wc * 64 + ni * 16 + (lane & 15);
      float phv = phr[u];
      float wvv = Wv[u];
#pragma unroll
      for (int mi = 0; mi < 2; ++mi) {
#pragma unroll
        for (int r = 0; r < 4; ++r) {
          float x = acc[mi][ni][r] + phv;
          cs[mi][r] += fast_tanh(x) * wvv;
        }
      }
    }
#pragma unroll
    for (int mi = 0; mi < 2; ++mi)
#pragma unroll
      for (int x = 0; x < 4; ++x) acc[mi][x] = fz;
  }

  // reduce cs across 16 column-lanes, deposit per-wc half, combine, store
#pragma unroll
  for (int mi = 0; mi < 2; ++mi) {
#pragma unroll
    for (int off = 1; off < 16; off <<= 1) {
#pragma unroll
      for (int r = 0; r < 4; ++r) cs[mi][r] += __shfl_xor(cs[mi][r], off);
    }
    if ((lane & 15) == 0) {
      int rloc = wr * 32 + mi * 16 + hi * 4;   // C layout: row = hi*4+r
#pragma unroll
      for (int r = 0; r < 4; ++r) csum[wc][rloc + r] = cs[mi][r];
    }
  }
  __syncthreads();
  if (tid < BM) logits[m0 + tid] = csum[0][tid] + csum[1][tid];
}

// ---------------- fused: softmax over L, then context[b,d] = sum_l w*F ----------------
__global__ void k_smctx(const float* __restrict__ logits, const float* __restrict__ F,
                        float* __restrict__ outw, float* __restrict__ ctx) {
  __shared__ float wl[L_];
  __shared__ f32x4 part[256];
  __shared__ float red[8];
  int b = blockIdx.x, t = threadIdx.x;
  float x = logits[(size_t)b * L_ + t];
  float m = x;
#pragma unroll
  for (int off = 32; off >= 1; off >>= 1) m = fmaxf(m, __shfl_xor(m, off));
  if ((t & 63) == 0) red[t >> 6] = m;
  __syncthreads();
  m = fmaxf(fmaxf(red[0], red[1]), fmaxf(red[2], red[3]));
  float e = __expf(x - m);
  float s = e;
#pragma unroll
  for (int off = 32; off >= 1; off >>= 1) s += __shfl_xor(s, off);
  if ((t & 63) == 0) red[4 + (t >> 6)] = s;
  __syncthreads();
  s = (red[4] + red[5]) + (red[6] + red[7]);
  float w = e / s;
  outw[(size_t)b * L_ + t] = w;
  wl[t] = w;
  __syncthreads();

  int lq = t >> 6, dq = t & 63;
  const f32x4* F4 = (const f32x4*)(F + (size_t)b * L_ * D_);
  f32x4 acc = {0.f, 0.f, 0.f, 0.f};
  for (int l = lq; l < L_; l += 4) acc += wl[l] * F4[l * 64 + dq];
  part[t] = acc;
  __syncthreads();
  if (lq == 0) {
    f32x4 r = (part[t] + part[t + 64]) + (part[t + 128] + part[t + 192]);
    ((f32x4*)ctx)[(size_t)b * 64 + dq] = r;
  }
}

extern "C" void kernel_launch(void* const* d_in, const int* in_sizes, int n_in,
                              void* d_out, int out_size, void* d_ws, size_t ws_size,
                              hipStream_t stream) {
  const float* F      = (const float*)d_in[0];
  const float* hidden = (const float*)d_in[1];
  const float* W1     = (const float*)d_in[2];
  const float* b1     = (const float*)d_in[3];
  const float* W2     = (const float*)d_in[4];
  const float* b2     = (const float*)d_in[5];
  const float* Wv     = (const float*)d_in[6];
  // d_in[7] = bv: shift-invariant under softmax, unused

  float* out_ctx = (float*)d_out;                 // [B,D]
  float* out_w   = out_ctx + (size_t)B_ * D_;     // [B,L]

  char* ws = (char*)d_ws;
  short* W1F    = (short*)ws;                     // 256 KB fragment-major bf16
  float* ph     = (float*)(ws + 262144);          // 2 MB fp32 [B,U]
  float* logits = (float*)(ws + 262144 + 2097152);// 1 MB fp32 [M_] (fully overwritten)

  k_w1f<<<512, 256, 0, stream>>>(W1, W1F);
  k_projh<<<dim3(2, 128), 256, 0, stream>>>(hidden, W2, b1, b2, ph);
  k_gemm<<<2048, 512, 0, stream>>>(F, W1F, ph, Wv, logits);
  k_smctx<<<1024, 256, 0, stream>>>(logits, F, out_w, out_ctx);
}